// Round 5
// baseline (205.408 us; speedup 1.0000x reference)
//
#include <hip/hip_runtime.h>

#define CB 4
#define CIN 256
#define COUT 256
#define HH 80
#define WW 80
#define HW (HH*WW)
#define K2 9
#define NKC 72            // K chunks = 2304/32
#define PXB 32            // pixels per deform block
#define NSTRIP (HW/PXB)   // 200 strips per image
#define NBLK (CB*NSTRIP)  // 800 deform blocks
#define LROW 40           // phase-3/1 LDS B row stride (elems)

typedef unsigned short ushort_t;
typedef __attribute__((ext_vector_type(8))) short bf16x8;
typedef __attribute__((ext_vector_type(4))) float f32x4;

__device__ __forceinline__ ushort_t f2bf(float f) {
    unsigned int b = __float_as_uint(f);
    b += 0x7fffu + ((b >> 16) & 1u);
    return (ushort_t)(b >> 16);
}
__device__ __forceinline__ float bflo(unsigned int u) { return __uint_as_float(u << 16); }
__device__ __forceinline__ float bfhi(unsigned int u) { return __uint_as_float(u & 0xffff0000u); }

__device__ __forceinline__ unsigned int blendpack(unsigned int a, unsigned int b,
                                                  unsigned int c, unsigned int d,
                                                  float w0, float w1, float w2, float w3) {
    float lo = w0*bflo(a) + w1*bflo(b) + w2*bflo(c) + w3*bflo(d);
    float hi = w0*bfhi(a) + w1*bfhi(b) + w2*bfhi(c) + w3*bfhi(d);
    unsigned int r;
    asm("v_cvt_pk_bf16_f32 %0, %1, %2" : "=v"(r) : "v"(lo), "v"(hi));
    return r;
}

// Fused prepass.
// blocks [0,1600): transpose NCHW fp32 -> NHWC bf16, 64px x 64ch tiles.
// blocks [1600,1616): pack conv_w (LDS-staged, coalesced reads).
// blocks [1616,1618): pack offset_w.
__global__ __launch_bounds__(256) void prep(const float* __restrict__ x,
                                            const float* __restrict__ conv_w,
                                            const float* __restrict__ offset_w,
                                            ushort_t* __restrict__ xb,
                                            ushort_t* __restrict__ wmain,
                                            ushort_t* __restrict__ woff) {
    const int tid = threadIdx.x;
    if (blockIdx.x < 1600) {
        __shared__ ushort_t tile[64*64];
        const int b   = blockIdx.x / 400;
        const int sub = blockIdx.x % 400;
        const int hw0 = (sub % 100) * 64;
        const int c0  = (sub / 100) * 64;
        const int px4 = (tid & 15) * 4;
        const int s   = tid & 7;              // = (px>>2)&7 for all 4 px
        const float* xp = x + ((size_t)b*CIN + c0)*HW + hw0 + px4;
        #pragma unroll
        for (int p = 0; p < 4; ++p) {
            const int cl = (tid >> 4) + p*16;
            const float4 v = *(const float4*)(xp + (size_t)cl*HW);
            const int cs = cl ^ (s << 3);
            tile[(px4+0)*64 + cs] = f2bf(v.x);
            tile[(px4+1)*64 + cs] = f2bf(v.y);
            tile[(px4+2)*64 + cs] = f2bf(v.z);
            tile[(px4+3)*64 + cs] = f2bf(v.w);
        }
        __syncthreads();
        const int g = tid & 7;
        #pragma unroll
        for (int p = 0; p < 2; ++p) {
            const int px = (tid >> 3) + p*32;
            const int sr = (px >> 2) & 7;
            const uint4 r = *(const uint4*)&tile[px*64 + ((g ^ sr) << 3)];
            *(uint4*)&xb[((size_t)b*HW + hw0 + px)*CIN + c0 + g*8] = r;
        }
    } else {
        const bool isOff = (blockIdx.x >= 1616);
        const int mt = isOff ? (int)(blockIdx.x - 1616) : (int)(blockIdx.x - 1600);
        const float* src = isOff ? offset_w : conv_w;
        ushort_t* dst = isOff ? woff : wmain;
        __shared__ ushort_t wlds[16*2312];    // 16 rows, padded stride 2312
        const int mbase = mt*16;
        // stage: fully coalesced float4 reads of [16][2304] fp32 -> LDS bf16
        for (int it = 0; it < 36; ++it) {
            const int f4 = it*256 + tid;
            const int ml = f4 / 576;          // 576 float4 per row
            const int inner = (f4 - ml*576) * 4;
            float4 v = make_float4(0.f,0.f,0.f,0.f);
            if (!isOff || (mbase + ml) < 18)
                v = *(const float4*)(src + ((size_t)(mbase + ml)*2304 + inner));
            ushort_t* wp = &wlds[ml*2312 + inner];
            wp[0] = f2bf(v.x); wp[1] = f2bf(v.y); wp[2] = f2bf(v.z); wp[3] = f2bf(v.w);
        }
        __syncthreads();
        // emit MFMA A-fragments: e = kc*64 + l
        for (int it = 0; it < 18; ++it) {
            const int e = it*256 + tid;
            const int kc = e >> 6, l = e & 63;
            const int ml = l & 15;
            const int kb = kc*32 + ((l >> 4) << 3);
            ushort_t v[8];
            #pragma unroll
            for (int i = 0; i < 8; ++i) {
                const int kg = kb + i;
                v[i] = wlds[ml*2312 + (kg & 255)*9 + (kg >> 8)];
            }
            uint4 r;
            r.x = v[0] | ((unsigned)v[1] << 16);
            r.y = v[2] | ((unsigned)v[3] << 16);
            r.z = v[4] | ((unsigned)v[5] << 16);
            r.w = v[6] | ((unsigned)v[7] << 16);
            const size_t o = isOff ? ((size_t)(kc*2 + mt)*64 + l)*8
                                   : ((size_t)(kc*16 + mt)*64 + l)*8;
            *(uint4*)&dst[o] = r;
        }
    }
}

// ---- phase-3 pipelined step (BUF = compile-time 0/1) ----
template<int BUF>
__device__ __forceinline__ void p3step(int kc, const ushort_t* __restrict__ xbase,
                                       const ushort_t* __restrict__ wmain,
                                       ushort_t* __restrict__ ldsB,
                                       const float (&bw)[K2][PXB][4], const int (&bi)[K2][PXB][4],
                                       uint2 &A0, uint2 &A1, uint2 &A2, uint2 &A3, float4 &wtA,
                                       bf16x8 (&afU)[4], bf16x8 (&afI)[4], f32x4 (&acc)[4][2],
                                       int pxg, int cg8, int lane, int mt0) {
    // 1. table read for kc+2 (LDS, 8-lane broadcast)
    float4 wtT; int4 ixT;
    const bool have = (kc + 2) < NKC;
    if (have) {
        const int tapT = (kc + 2) >> 3;
        wtT = *(const float4*)bw[tapT][pxg];
        ixT = *(const int4*)bi[tapT][pxg];
    }
    // 2. A-fragments for kc+1 (global, L2-hot)
    if (kc + 1 < NKC) {
        #pragma unroll
        for (int mi = 0; mi < 4; ++mi)
            afI[mi] = *(const bf16x8*)(wmain + ((size_t)((kc+1)*16 + mt0 + mi)*64 + lane)*8);
    }
    // 3. blend current corners (issued 2 chunks ago) -> LDS
    uint2 r;
    r.x = blendpack(A0.x, A1.x, A2.x, A3.x, wtA.x, wtA.y, wtA.z, wtA.w);
    r.y = blendpack(A0.y, A1.y, A2.y, A3.y, wtA.x, wtA.y, wtA.z, wtA.w);
    *(uint2*)&ldsB[BUF*PXB*LROW + pxg*LROW + cg8*4] = r;
    // 4. issue corner loads for kc+2 (vmcnt floats across the barrier)
    if (have) {
        const int c0n = ((kc+2) & 7)*32 + cg8*4;
        A0 = *(const uint2*)(xbase + ixT.x + c0n);
        A1 = *(const uint2*)(xbase + ixT.y + c0n);
        A2 = *(const uint2*)(xbase + ixT.z + c0n);
        A3 = *(const uint2*)(xbase + ixT.w + c0n);
        wtA = wtT;
    }
    // 5. LDS drain + barrier (no vmcnt drain)
    asm volatile("s_waitcnt lgkmcnt(0)" ::: "memory");
    __builtin_amdgcn_s_barrier();
    // 6. B fragments + 8 MFMA
    bf16x8 bfr[2];
    #pragma unroll
    for (int ni = 0; ni < 2; ++ni)
        bfr[ni] = *(const bf16x8*)&ldsB[BUF*PXB*LROW + (ni*16 + (lane&15))*LROW + (lane>>4)*8];
    #pragma unroll
    for (int mi = 0; mi < 4; ++mi)
        #pragma unroll
        for (int ni = 0; ni < 2; ++ni)
            acc[mi][ni] = __builtin_amdgcn_mfma_f32_16x16x32_bf16(afU[mi], bfr[ni], acc[mi][ni], 0, 0, 0);
}

__global__ __launch_bounds__(256) void deform_main(const ushort_t* __restrict__ xb,
                                                   const ushort_t* __restrict__ wmain,
                                                   const ushort_t* __restrict__ woff,
                                                   const float* __restrict__ offset_b,
                                                   const float* __restrict__ conv_b,
                                                   float* __restrict__ out) {
    // pool: phase1 = 4 waves x 2 bufs x 16*LROW els (10240B); phase3 = 2 x PXB*LROW els (5120B)
    __shared__ __align__(16) ushort_t lds_pool[4*2*16*LROW];
    __shared__ float off_lds[18][PXB];
    __shared__ float bw[K2][PXB][4];
    __shared__ int   bi[K2][PXB][4];

    const int tid = threadIdx.x;
    const int lane = tid & 63;
    const int wv = tid >> 6;
    // XCD-aware swizzle: 800 % 8 == 0 -> bijective; each XCD owns 100 contiguous strips (40 rows)
    const int sb = (blockIdx.x & 7) * (NBLK/8) + (blockIdx.x >> 3);
    const int bb = sb / NSTRIP;
    const int hwb = (sb % NSTRIP) * PXB;
    const ushort_t* xbase = xb + (size_t)bb * HW * CIN;

    // ---------- phase 1: offset conv, wave-private tiles, zero barriers, PF=2 ----------
    {
        const int mt = wv >> 1;            // 0..1 (m half of padded 32)
        const int nt = wv & 1;             // pixel half
        ushort_t* myB = lds_pool + wv * (2*16*LROW);
        f32x4 a0 = {0.f,0.f,0.f,0.f};
        const int pxl = lane >> 2;         // 0..15
        const int cgp = lane & 3;          // uint4 = 8 els -> 32 k
        const int hw = hwb + nt*16 + pxl;
        const int ph = hw / WW, pw = hw - ph*WW;

        uint4 u0, u1;
        #define P1LOAD(U, KC_) { \
            const int tap_ = (KC_) >> 3; \
            const int c0_ = ((KC_) & 7)*32 + cgp*8; \
            const int yy_ = ph + tap_/3 - 1, xx_ = pw + tap_%3 - 1; \
            U = make_uint4(0u,0u,0u,0u); \
            if (yy_ >= 0 && yy_ < HH && xx_ >= 0 && xx_ < WW) \
                U = *(const uint4*)(xbase + (yy_*WW + xx_)*CIN + c0_); }

        P1LOAD(u0, 0);
        P1LOAD(u1, 1);
        for (int kp = 0; kp < NKC/2; ++kp) {
            {
                const int kc = 2*kp;
                const bf16x8 af = *(const bf16x8*)(woff + ((size_t)(kc*2 + mt)*64 + lane)*8);
                *(uint4*)&myB[pxl*LROW + cgp*8] = u0;
                if (kp + 1 < NKC/2) P1LOAD(u0, 2*kp + 2);
                const bf16x8 b0 = *(const bf16x8*)&myB[(lane&15)*LROW + (lane>>4)*8];
                a0 = __builtin_amdgcn_mfma_f32_16x16x32_bf16(af, b0, a0, 0, 0, 0);
            }
            {
                const int kc = 2*kp + 1;
                const bf16x8 af = *(const bf16x8*)(woff + ((size_t)(kc*2 + mt)*64 + lane)*8);
                *(uint4*)&myB[16*LROW + pxl*LROW + cgp*8] = u1;
                if (kp + 1 < NKC/2) P1LOAD(u1, 2*kp + 3);
                const bf16x8 b0 = *(const bf16x8*)&myB[16*LROW + (lane&15)*LROW + (lane>>4)*8];
                a0 = __builtin_amdgcn_mfma_f32_16x16x32_bf16(af, b0, a0, 0, 0, 0);
            }
        }
        #undef P1LOAD
        const int r0 = (lane >> 4) * 4;
        #pragma unroll
        for (int j = 0; j < 4; ++j) {
            const int oc = mt*16 + r0 + j;
            if (oc < 18)
                off_lds[oc][nt*16 + (lane & 15)] = a0[j] + offset_b[oc];
        }
    }
    __syncthreads();

    // ---------- phase 2: bilinear weights/indices (9 taps x 32 px) ----------
    for (int it = tid; it < K2*PXB; it += 256) {
        const int tap = it >> 5, pxl = it & 31;
        const int hw = hwb + pxl;
        const int ph = hw / WW, pw = hw - ph*WW;
        const float dy = off_lds[tap*2][pxl];
        const float dx = off_lds[tap*2 + 1][pxl];
        const float py  = (float)(ph + tap/3 - 1) + dy;
        const float pxx = (float)(pw + tap%3 - 1) + dx;
        const float y0f = floorf(py), x0f = floorf(pxx);
        const float wy = py - y0f, wx = pxx - x0f;
        const int y0 = (int)y0f, x0 = (int)x0f;
        const int y1 = y0 + 1, x1 = x0 + 1;
        const float vy0 = (y0 >= 0 && y0 < HH) ? 1.f : 0.f;
        const float vy1 = (y1 >= 0 && y1 < HH) ? 1.f : 0.f;
        const float vx0 = (x0 >= 0 && x0 < WW) ? 1.f : 0.f;
        const float vx1 = (x1 >= 0 && x1 < WW) ? 1.f : 0.f;
        const int y0c = min(max(y0, 0), HH-1), y1c = min(max(y1, 0), HH-1);
        const int x0c = min(max(x0, 0), WW-1), x1c = min(max(x1, 0), WW-1);
        bw[tap][pxl][0] = (1.f-wy)*(1.f-wx)*vy0*vx0;
        bw[tap][pxl][1] = (1.f-wy)*wx*vy0*vx1;
        bw[tap][pxl][2] = wy*(1.f-wx)*vy1*vx0;
        bw[tap][pxl][3] = wy*wx*vy1*vx1;
        bi[tap][pxl][0] = (y0c*WW + x0c)*CIN;
        bi[tap][pxl][1] = (y0c*WW + x1c)*CIN;
        bi[tap][pxl][2] = (y1c*WW + x0c)*CIN;
        bi[tap][pxl][3] = (y1c*WW + x1c)*CIN;
    }
    __syncthreads();

    // ---------- phase 3: main deformable GEMM, PF=2 corners + PF=1 A-frags ----------
    f32x4 acc[4][2];
    #pragma unroll
    for (int mi = 0; mi < 4; ++mi)
        #pragma unroll
        for (int ni = 0; ni < 2; ++ni)
            acc[mi][ni] = (f32x4){0.f,0.f,0.f,0.f};

    ushort_t* ldsB = lds_pool;
    const int mt0 = wv * 4;
    const int pxg = tid >> 3, cg8 = tid & 7;   // thread covers 4 k (uint2, 8B)
    float4 wtA, wtB;
    uint2 A0, A1, A2, A3, B0, B1, B2, B3;
    bf16x8 afA[4], afB[4];
    {   // prologue: corners(0)->A, corners(1)->B, A-frags(0)->afA
        wtA = *(const float4*)bw[0][pxg];
        const int4 ix0 = *(const int4*)bi[0][pxg];
        const int c00 = cg8*4;
        A0 = *(const uint2*)(xbase + ix0.x + c00);
        A1 = *(const uint2*)(xbase + ix0.y + c00);
        A2 = *(const uint2*)(xbase + ix0.z + c00);
        A3 = *(const uint2*)(xbase + ix0.w + c00);
        wtB = wtA;
        const int c01 = 32 + cg8*4;
        B0 = *(const uint2*)(xbase + ix0.x + c01);
        B1 = *(const uint2*)(xbase + ix0.y + c01);
        B2 = *(const uint2*)(xbase + ix0.z + c01);
        B3 = *(const uint2*)(xbase + ix0.w + c01);
        #pragma unroll
        for (int mi = 0; mi < 4; ++mi)
            afA[mi] = *(const bf16x8*)(wmain + ((size_t)(mt0 + mi)*64 + lane)*8);
    }
    for (int kp = 0; kp < NKC/2; ++kp) {
        p3step<0>(2*kp,     xbase, wmain, ldsB, bw, bi, A0, A1, A2, A3, wtA, afA, afB, acc, pxg, cg8, lane, mt0);
        p3step<1>(2*kp + 1, xbase, wmain, ldsB, bw, bi, B0, B1, B2, B3, wtB, afB, afA, acc, pxg, cg8, lane, mt0);
    }

    // epilogue: D col = lane&15 (pixel), row = (lane>>4)*4+j (out channel)
    #pragma unroll
    for (int mi = 0; mi < 4; ++mi) {
        #pragma unroll
        for (int ni = 0; ni < 2; ++ni) {
            const int pxl = ni*16 + (lane & 15);
            #pragma unroll
            for (int j = 0; j < 4; ++j) {
                const int o = (mt0 + mi)*16 + (lane >> 4)*4 + j;
                out[((size_t)bb*COUT + o)*HW + hwb + pxl] = acc[mi][ni][j] + conv_b[o];
            }
        }
    }
}

extern "C" void kernel_launch(void* const* d_in, const int* in_sizes, int n_in,
                              void* d_out, int out_size, void* d_ws, size_t ws_size,
                              hipStream_t stream) {
    const float* x        = (const float*)d_in[0];
    const float* offset_w = (const float*)d_in[1];
    const float* offset_b = (const float*)d_in[2];
    const float* conv_w   = (const float*)d_in[3];
    const float* conv_b   = (const float*)d_in[4];
    float* out = (float*)d_out;

    char* wsb = (char*)d_ws;
    ushort_t* xb    = (ushort_t*)wsb;
    ushort_t* wmain = (ushort_t*)(wsb + (size_t)CB*HW*CIN*2);
    ushort_t* woff  = (ushort_t*)(wsb + (size_t)CB*HW*CIN*2 + (size_t)NKC*16*64*8*2);

    hipLaunchKernelGGL(prep, dim3(1618), dim3(256), 0, stream,
                       x, conv_w, offset_w, xb, wmain, woff);
    hipLaunchKernelGGL(deform_main, dim3(NBLK), dim3(256), 0, stream,
                       xb, wmain, woff, offset_b, conv_b, out);
}

// Round 6
// 181.781 us; speedup vs baseline: 1.1300x; 1.1300x over previous
//
#include <hip/hip_runtime.h>

#define CB 4
#define CIN 256
#define COUT 256
#define HH 80
#define WW 80
#define HW (HH*WW)
#define K2 9
#define NKC 72          // K chunks = 2304/32
#define LDSROW 56       // phase-3 B-tile row stride (elems)
#define NSTRIP (HW/64)  // 100 strips per image
#define NBLK (CB*NSTRIP)

typedef unsigned short ushort_t;
typedef __attribute__((ext_vector_type(8))) _Float16 f16x8;
typedef __attribute__((ext_vector_type(2))) _Float16 h2;
typedef __attribute__((ext_vector_type(4))) float f32x4;

__device__ __forceinline__ ushort_t f2h(float f) {
    _Float16 h = (_Float16)f;
    return *(ushort_t*)&h;
}

// f16 packed bilinear blend: one word = 2 channels; 4 packed ops total.
__device__ __forceinline__ unsigned int blend2(unsigned int a, unsigned int b,
                                               unsigned int c, unsigned int d,
                                               h2 w0, h2 w1, h2 w2, h2 w3) {
    h2 r = *(h2*)&a * w0;
    r += *(h2*)&b * w1;
    r += *(h2*)&c * w2;
    r += *(h2*)&d * w3;
    return *(unsigned int*)&r;
}

// Fused prepass: blocks [0,1600) transpose NCHW fp32 -> NHWC f16; [1600,1618) pack weights.
__global__ __launch_bounds__(256) void prep(const float* __restrict__ x,
                                            const float* __restrict__ conv_w,
                                            const float* __restrict__ offset_w,
                                            ushort_t* __restrict__ xb,
                                            ushort_t* __restrict__ wmain,
                                            ushort_t* __restrict__ woff) {
    const int tid = threadIdx.x;
    if (blockIdx.x < 1600) {
        __shared__ ushort_t tile[64*64];
        const int b   = blockIdx.x / 400;
        const int sub = blockIdx.x % 400;
        const int hw0 = (sub % 100) * 64;
        const int c0  = (sub / 100) * 64;
        const int px4 = (tid & 15) * 4;
        const int s   = tid & 7;
        const float* xp = x + ((size_t)b*CIN + c0)*HW + hw0 + px4;
        #pragma unroll
        for (int p = 0; p < 4; ++p) {
            const int cl = (tid >> 4) + p*16;
            const float4 v = *(const float4*)(xp + (size_t)cl*HW);
            const int cs = cl ^ (s << 3);
            tile[(px4+0)*64 + cs] = f2h(v.x);
            tile[(px4+1)*64 + cs] = f2h(v.y);
            tile[(px4+2)*64 + cs] = f2h(v.z);
            tile[(px4+3)*64 + cs] = f2h(v.w);
        }
        __syncthreads();
        const int g = tid & 7;
        #pragma unroll
        for (int p = 0; p < 2; ++p) {
            const int px = (tid >> 3) + p*32;
            const int sr = (px >> 2) & 7;
            const uint4 r = *(const uint4*)&tile[px*64 + ((g ^ sr) << 3)];
            *(uint4*)&xb[((size_t)b*HW + hw0 + px)*CIN + c0 + g*8] = r;
        }
    } else {
        const bool isOff = (blockIdx.x >= 1616);
        const int mt = isOff ? (int)(blockIdx.x - 1616) : (int)(blockIdx.x - 1600);
        const float* src = isOff ? offset_w : conv_w;
        ushort_t* dst = isOff ? woff : wmain;
        __shared__ ushort_t wlds[16*2312];
        const int mbase = mt*16;
        for (int it = 0; it < 36; ++it) {
            const int f4 = it*256 + tid;
            const int ml = f4 / 576;
            const int inner = (f4 - ml*576) * 4;
            float4 v = make_float4(0.f,0.f,0.f,0.f);
            if (!isOff || (mbase + ml) < 18)
                v = *(const float4*)(src + ((size_t)(mbase + ml)*2304 + inner));
            ushort_t* wp = &wlds[ml*2312 + inner];
            wp[0] = f2h(v.x); wp[1] = f2h(v.y); wp[2] = f2h(v.z); wp[3] = f2h(v.w);
        }
        __syncthreads();
        for (int it = 0; it < 18; ++it) {
            const int e = it*256 + tid;
            const int kc = e >> 6, l = e & 63;
            const int ml = l & 15;
            const int kb = kc*32 + ((l >> 4) << 3);
            ushort_t v[8];
            #pragma unroll
            for (int i = 0; i < 8; ++i) {
                const int kg = kb + i;
                v[i] = wlds[ml*2312 + (kg & 255)*9 + (kg >> 8)];
            }
            uint4 r;
            r.x = v[0] | ((unsigned)v[1] << 16);
            r.y = v[2] | ((unsigned)v[3] << 16);
            r.z = v[4] | ((unsigned)v[5] << 16);
            r.w = v[6] | ((unsigned)v[7] << 16);
            const size_t o = isOff ? ((size_t)(kc*2 + mt)*64 + l)*8
                                   : ((size_t)(kc*16 + mt)*64 + l)*8;
            *(uint4*)&dst[o] = r;
        }
    }
}

// ---- phase-3 pipelined step (BUF = compile-time 0/1) ----
template<int BUF>
__device__ __forceinline__ void p3step(int kc, const ushort_t* __restrict__ xbase,
                                       const ushort_t* __restrict__ wmain,
                                       ushort_t* __restrict__ ldsB,
                                       const uint4 (&bwp)[K2][64], const int4 (&bip)[K2][64],
                                       uint4 &A0, uint4 &A1, uint4 &A2, uint4 &A3, uint4 &wtA,
                                       f16x8 (&afU)[4], f16x8 (&afI)[4], f32x4 (&acc)[4][4],
                                       int pxg, int cg, int lane, int mt0) {
    // 1. table read for kc+2 (LDS)
    uint4 wtT; int4 ixT;
    const bool have = (kc + 2) < NKC;
    if (have) {
        const int tapT = (kc + 2) >> 3;
        wtT = bwp[tapT][pxg];
        ixT = bip[tapT][pxg];
    }
    // 2. A-fragments for kc+1 (global, L2-hot)
    if (kc + 1 < NKC) {
        #pragma unroll
        for (int mi = 0; mi < 4; ++mi)
            afI[mi] = *(const f16x8*)(wmain + ((size_t)((kc+1)*16 + mt0 + mi)*64 + lane)*8);
    }
    // 3. blend current corners (issued 2 chunks ago) -> LDS  [4 pk-ops/word]
    {
        const h2 w0 = *(h2*)&wtA.x, w1 = *(h2*)&wtA.y, w2 = *(h2*)&wtA.z, w3 = *(h2*)&wtA.w;
        uint4 r;
        r.x = blend2(A0.x, A1.x, A2.x, A3.x, w0, w1, w2, w3);
        r.y = blend2(A0.y, A1.y, A2.y, A3.y, w0, w1, w2, w3);
        r.z = blend2(A0.z, A1.z, A2.z, A3.z, w0, w1, w2, w3);
        r.w = blend2(A0.w, A1.w, A2.w, A3.w, w0, w1, w2, w3);
        *(uint4*)&ldsB[BUF*64*LDSROW + pxg*LDSROW + cg*8] = r;
    }
    // 4. issue corner loads for kc+2 (vmcnt floats across the barrier)
    if (have) {
        const int c0n = ((kc+2) & 7)*32 + cg*8;
        A0 = *(const uint4*)(xbase + ixT.x + c0n);
        A1 = *(const uint4*)(xbase + ixT.y + c0n);
        A2 = *(const uint4*)(xbase + ixT.z + c0n);
        A3 = *(const uint4*)(xbase + ixT.w + c0n);
        wtA = wtT;
    }
    // 5. LDS drain + barrier (no vmcnt drain)
    asm volatile("s_waitcnt lgkmcnt(0)" ::: "memory");
    __builtin_amdgcn_s_barrier();
    // 6. B fragments + 16 MFMA
    f16x8 bfr[4];
    #pragma unroll
    for (int ni = 0; ni < 4; ++ni)
        bfr[ni] = *(const f16x8*)&ldsB[BUF*64*LDSROW + (ni*16 + (lane&15))*LDSROW + (lane>>4)*8];
    #pragma unroll
    for (int mi = 0; mi < 4; ++mi)
        #pragma unroll
        for (int ni = 0; ni < 4; ++ni)
            acc[mi][ni] = __builtin_amdgcn_mfma_f32_16x16x32_f16(afU[mi], bfr[ni], acc[mi][ni], 0, 0, 0);
}

__global__ __launch_bounds__(256) void deform_main(const ushort_t* __restrict__ xb,
                                                   const ushort_t* __restrict__ wmain,
                                                   const ushort_t* __restrict__ woff,
                                                   const float* __restrict__ offset_b,
                                                   const float* __restrict__ conv_b,
                                                   float* __restrict__ out) {
    // phase1 view: 4 waves x 2 bufs x [32][40] f16 (20480B); phase3 view: [2][64*LDSROW] (14336B)
    __shared__ __align__(16) char lds_pool[20480];
    __shared__ float off_lds[18][64];
    __shared__ uint4 bwp[K2][64];
    __shared__ int4  bip[K2][64];

    const int tid = threadIdx.x;
    const int lane = tid & 63;
    const int wv = tid >> 6;
    // XCD-aware swizzle: 400 % 8 == 0 -> bijective
    const int sb = (blockIdx.x & 7) * (NBLK/8) + (blockIdx.x >> 3);
    const int bb = sb / NSTRIP;
    const int hwb = (sb % NSTRIP) * 64;
    const ushort_t* xbase = xb + (size_t)bb * HW * CIN;
    const int pxg = tid >> 2, cg = tid & 3;

    // ---------- phase 1: offset conv, wave-private LDS tiles, zero barriers, PF=2 ----------
    {
        const int mt = wv >> 1;
        const int p0 = (wv & 1) * 32;
        ushort_t* myB = (ushort_t*)lds_pool + wv * 2560;
        f32x4 a0 = {0.f,0.f,0.f,0.f}, a1 = {0.f,0.f,0.f,0.f};
        const int pxl = lane >> 1;
        const int ch  = lane & 1;
        const int hw = hwb + p0 + pxl;
        const int ph = hw / WW, pw = hw - ph*WW;

        uint4 u0a, u0b, u1a, u1b;
        #define P1LOAD(UA, UB, KC_) { \
            const int tap_ = (KC_) >> 3; \
            const int c0_ = ((KC_) & 7)*32 + ch*16; \
            const int yy_ = ph + tap_/3 - 1, xx_ = pw + tap_%3 - 1; \
            UA = make_uint4(0u,0u,0u,0u); UB = make_uint4(0u,0u,0u,0u); \
            if (yy_ >= 0 && yy_ < HH && xx_ >= 0 && xx_ < WW) { \
                const ushort_t* p_ = xbase + (yy_*WW + xx_)*CIN + c0_; \
                UA = *(const uint4*)p_; UB = *(const uint4*)(p_ + 8); } }

        P1LOAD(u0a, u0b, 0);
        P1LOAD(u1a, u1b, 1);
        for (int kp = 0; kp < NKC/2; ++kp) {
            {
                const int kc = 2*kp;
                const f16x8 af = *(const f16x8*)(woff + ((size_t)(kc*2 + mt)*64 + lane)*8);
                ushort_t* wb = myB + pxl*40 + ch*16;
                *(uint4*)wb = u0a;
                *(uint4*)(wb + 8) = u0b;
                if (kp + 1 < NKC/2) P1LOAD(u0a, u0b, 2*kp + 2);
                const f16x8 b0 = *(const f16x8*)(myB + (lane&15)*40 + (lane>>4)*8);
                const f16x8 b1 = *(const f16x8*)(myB + (16 + (lane&15))*40 + (lane>>4)*8);
                a0 = __builtin_amdgcn_mfma_f32_16x16x32_f16(af, b0, a0, 0, 0, 0);
                a1 = __builtin_amdgcn_mfma_f32_16x16x32_f16(af, b1, a1, 0, 0, 0);
            }
            {
                const int kc = 2*kp + 1;
                const f16x8 af = *(const f16x8*)(woff + ((size_t)(kc*2 + mt)*64 + lane)*8);
                ushort_t* wb = myB + 1280 + pxl*40 + ch*16;
                *(uint4*)wb = u1a;
                *(uint4*)(wb + 8) = u1b;
                if (kp + 1 < NKC/2) P1LOAD(u1a, u1b, 2*kp + 3);
                const f16x8 b0 = *(const f16x8*)(myB + 1280 + (lane&15)*40 + (lane>>4)*8);
                const f16x8 b1 = *(const f16x8*)(myB + 1280 + (16 + (lane&15))*40 + (lane>>4)*8);
                a0 = __builtin_amdgcn_mfma_f32_16x16x32_f16(af, b0, a0, 0, 0, 0);
                a1 = __builtin_amdgcn_mfma_f32_16x16x32_f16(af, b1, a1, 0, 0, 0);
            }
        }
        #undef P1LOAD
        const int r0 = (lane >> 4) * 4;
        #pragma unroll
        for (int j = 0; j < 4; ++j) {
            const int oc = mt*16 + r0 + j;
            if (oc < 18) {
                const float ob = offset_b[oc];
                off_lds[oc][p0 + (lane & 15)]      = a0[j] + ob;
                off_lds[oc][p0 + 16 + (lane & 15)] = a1[j] + ob;
            }
        }
    }
    __syncthreads();

    // ---------- phase 2: bilinear weights (packed f16 pairs) + indices ----------
    for (int it = tid; it < K2*64; it += 256) {
        const int tap = it >> 6, pxl = it & 63;
        const int hw = hwb + pxl;
        const int ph = hw / WW, pw = hw - ph*WW;
        const float dy = off_lds[tap*2][pxl];
        const float dx = off_lds[tap*2 + 1][pxl];
        const float py  = (float)(ph + tap/3 - 1) + dy;
        const float pxx = (float)(pw + tap%3 - 1) + dx;
        const float y0f = floorf(py), x0f = floorf(pxx);
        const float wy = py - y0f, wx = pxx - x0f;
        const int y0 = (int)y0f, x0 = (int)x0f;
        const int y1 = y0 + 1, x1 = x0 + 1;
        const float vy0 = (y0 >= 0 && y0 < HH) ? 1.f : 0.f;
        const float vy1 = (y1 >= 0 && y1 < HH) ? 1.f : 0.f;
        const float vx0 = (x0 >= 0 && x0 < WW) ? 1.f : 0.f;
        const float vx1 = (x1 >= 0 && x1 < WW) ? 1.f : 0.f;
        const int y0c = min(max(y0, 0), HH-1), y1c = min(max(y1, 0), HH-1);
        const int x0c = min(max(x0, 0), WW-1), x1c = min(max(x1, 0), WW-1);
        const float W00 = (1.f-wy)*(1.f-wx)*vy0*vx0;
        const float W01 = (1.f-wy)*wx*vy0*vx1;
        const float W10 = wy*(1.f-wx)*vy1*vx0;
        const float W11 = wy*wx*vy1*vx1;
        uint4 wv4;
        { h2 t = {(_Float16)W00, (_Float16)W00}; wv4.x = *(unsigned int*)&t; }
        { h2 t = {(_Float16)W01, (_Float16)W01}; wv4.y = *(unsigned int*)&t; }
        { h2 t = {(_Float16)W10, (_Float16)W10}; wv4.z = *(unsigned int*)&t; }
        { h2 t = {(_Float16)W11, (_Float16)W11}; wv4.w = *(unsigned int*)&t; }
        bwp[tap][pxl] = wv4;
        bip[tap][pxl] = make_int4((y0c*WW + x0c)*CIN, (y0c*WW + x1c)*CIN,
                                  (y1c*WW + x0c)*CIN, (y1c*WW + x1c)*CIN);
    }
    __syncthreads();

    // ---------- phase 3: main deformable GEMM, PF=2 corners + PF=1 A-frags ----------
    f32x4 acc[4][4];
    #pragma unroll
    for (int mi = 0; mi < 4; ++mi)
        #pragma unroll
        for (int ni = 0; ni < 4; ++ni)
            acc[mi][ni] = (f32x4){0.f,0.f,0.f,0.f};

    ushort_t* ldsB = (ushort_t*)lds_pool;
    const int mt0 = wv * 4;
    uint4 wtA, wtB;
    uint4 A0, A1, A2, A3, B0, B1, B2, B3;
    f16x8 afA[4], afB[4];
    {   // prologue: corners(0)->A, corners(1)->B (tap 0 for both), A-frags(0)->afA
        wtA = bwp[0][pxg];
        const int4 ix0 = bip[0][pxg];
        const int c00 = cg*8;
        A0 = *(const uint4*)(xbase + ix0.x + c00);
        A1 = *(const uint4*)(xbase + ix0.y + c00);
        A2 = *(const uint4*)(xbase + ix0.z + c00);
        A3 = *(const uint4*)(xbase + ix0.w + c00);
        wtB = wtA;
        const int c01 = 32 + cg*8;
        B0 = *(const uint4*)(xbase + ix0.x + c01);
        B1 = *(const uint4*)(xbase + ix0.y + c01);
        B2 = *(const uint4*)(xbase + ix0.z + c01);
        B3 = *(const uint4*)(xbase + ix0.w + c01);
        #pragma unroll
        for (int mi = 0; mi < 4; ++mi)
            afA[mi] = *(const f16x8*)(wmain + ((size_t)(mt0 + mi)*64 + lane)*8);
    }
    for (int kp = 0; kp < NKC/2; ++kp) {
        p3step<0>(2*kp,     xbase, wmain, ldsB, bwp, bip, A0, A1, A2, A3, wtA, afA, afB, acc, pxg, cg, lane, mt0);
        p3step<1>(2*kp + 1, xbase, wmain, ldsB, bwp, bip, B0, B1, B2, B3, wtB, afB, afA, acc, pxg, cg, lane, mt0);
    }

    // epilogue: D col = lane&15 (pixel), row = (lane>>4)*4+j (out channel)
    #pragma unroll
    for (int mi = 0; mi < 4; ++mi) {
        #pragma unroll
        for (int ni = 0; ni < 4; ++ni) {
            const int pxl = ni*16 + (lane & 15);
            #pragma unroll
            for (int j = 0; j < 4; ++j) {
                const int o = (mt0 + mi)*16 + (lane >> 4)*4 + j;
                out[((size_t)bb*COUT + o)*HW + hwb + pxl] = acc[mi][ni][j] + conv_b[o];
            }
        }
    }
}

extern "C" void kernel_launch(void* const* d_in, const int* in_sizes, int n_in,
                              void* d_out, int out_size, void* d_ws, size_t ws_size,
                              hipStream_t stream) {
    const float* x        = (const float*)d_in[0];
    const float* offset_w = (const float*)d_in[1];
    const float* offset_b = (const float*)d_in[2];
    const float* conv_w   = (const float*)d_in[3];
    const float* conv_b   = (const float*)d_in[4];
    float* out = (float*)d_out;

    char* wsb = (char*)d_ws;
    ushort_t* xb    = (ushort_t*)wsb;
    ushort_t* wmain = (ushort_t*)(wsb + (size_t)CB*HW*CIN*2);
    ushort_t* woff  = (ushort_t*)(wsb + (size_t)CB*HW*CIN*2 + (size_t)NKC*16*64*8*2);

    hipLaunchKernelGGL(prep, dim3(1618), dim3(256), 0, stream,
                       x, conv_w, offset_w, xb, wmain, woff);
    hipLaunchKernelGGL(deform_main, dim3(NBLK), dim3(256), 0, stream,
                       xb, wmain, woff, offset_b, conv_b, out);
}